// Round 9
// baseline (8333.661 us; speedup 1.0000x reference)
//
#include <hip/hip_runtime.h>
#include <hip/hip_fp16.h>

#define T_STEPS 2048
#define B_SZ 128
#define I_SZ 10
#define H_SZ 512

#define NGRP 8            // batch groups (16 rows each)
#define GWG 8             // wgs per group
#define NWG (NGRP * GWG)  // 64 workgroups
#define BSLICE 16         // batch rows per group
#define WCOL 64           // hidden cols per wg
#define NTHR 512

typedef _Float16 f16x8 __attribute__((ext_vector_type(8)));
typedef float f32x4 __attribute__((ext_vector_type(4)));
typedef float f32x2 __attribute__((ext_vector_type(2)));
typedef unsigned u32x4 __attribute__((ext_vector_type(4)));
typedef unsigned long long u64t;

// Tagged h buffers: [2][NGRP][BSLICE][H/2] u64, u64 = (tag << 32) | 2xfp16.
// MUST be zeroed before every persistent launch: stale tags from a previous
// replay (or 0xAA poison = tag 0xAAAAAAAA) would satisfy the tag check.
__global__ void clear_hbuf_kernel(u64t* p) {
    const int i = blockIdx.x * 256 + threadIdx.x;   // 16384 threads
    #pragma unroll
    for (int k = 0; k < 4; ++k)
        __hip_atomic_store(p + i + k * 16384, 0ull,
                           __ATOMIC_RELAXED, __HIP_MEMORY_SCOPE_AGENT);
}

// Persistent LSTM, tagged-payload sync on the R8 LDS-staging topology.
//
//   8 independent batch-groups x 8 wgs; wg owns 64 hidden cols (all 4 gates,
//   full K) of its group's 16 batch rows. Per step each wg stages the
//   group's 16x512 fp16 h-slice into LDS from the TAGGED buffer: each of
//   512 staging threads owns one 64B chunk (4 x dwordx4 sc0 sc1 = 8 tagged
//   u64), validates 8 tags, retries ONLY its own chunk (done lanes are
//   exec-masked off) — detection and data arrive in the same LLC read.
//   Producers fire-and-forget one tagged u64 store per thread: no vmcnt
//   drain, no flag array, no release barrier. Two __syncthreads per step.
//
// Double-buffer safety (skew <= 1 step): publish at end of step s writes
// tag s+2 into buf[(s+1)&1]. Overwriting buf[p] next happens at end of step
// s+2, which follows staging(s+2) (needs ALL tags s+3, i.e. every wg
// finished step s+1, i.e. every wg's staging-reads of buf[p] at step s+1
// are done). Intra-line atomicity: each 8B granule is written by a single
// store; dwordx4 reads cannot observe a torn tag/payload pair.
__global__ __launch_bounds__(NTHR, 2) void lstm_persistent(
    const float* __restrict__ x,     // [T,B,I]
    const float* __restrict__ hx,    // [B,H]
    const float* __restrict__ cx,    // [B,H]
    const float* __restrict__ W_ih,  // [4H,I]
    const float* __restrict__ W_hh,  // [4H,H]
    const float* __restrict__ b_ih,  // [4H]
    const float* __restrict__ b_hh,  // [4H]
    float* __restrict__ out,         // [3*B*H] = h, h, c
    u64t* hbuf)                      // [2][NGRP][BSLICE][H/2] tagged
{
    __shared__ _Float16 h_stage[BSLICE][520];   // +8 fp16 pad
    __shared__ float lds_g[4 * WCOL][17];       // [gate*64+col][row], padded

    const int wg   = blockIdx.x;
    const int g    = wg >> 3;          // batch group 0..7
    const int wgin = wg & 7;           // wg within group 0..7
    const int tid  = threadIdx.x;
    const int wid  = tid >> 6;         // wave 0..7
    const int lane = tid & 63;
    const int fr_col = lane & 15;
    const int fr_kg  = lane >> 4;      // 0..3

    // ---- this wave's two gate-column fragments (wg covers 256 gate-cols)
    int gcL[2], wr[2];
    #pragma unroll
    for (int f = 0; f < 2; ++f) {
        gcL[f] = wid * 32 + f * 16 + fr_col;              // 0..255
        wr[f]  = (gcL[f] >> 6) * H_SZ + wgin * WCOL + (gcL[f] & 63);
    }

    // ---- W_hh B-fragments: 2 frags x 16 K-chunks, fp16 register-resident
    f16x8 wf[2][16];
    #pragma unroll
    for (int f = 0; f < 2; ++f)
        #pragma unroll
        for (int c = 0; c < 16; ++c) {
            const float* p = W_hh + (size_t)wr[f] * H_SZ + c * 32 + fr_kg * 8;
            f16x8 w;
            #pragma unroll
            for (int e = 0; e < 8; ++e) w[e] = (_Float16)p[e];
            wf[f][c] = w;
        }

    // ---- W_ih rows + combined bias
    float wih[2][I_SZ], bias[2];
    #pragma unroll
    for (int f = 0; f < 2; ++f) {
        #pragma unroll
        for (int i = 0; i < I_SZ; ++i) wih[f][i] = W_ih[wr[f] * I_SZ + i];
        bias[f] = b_ih[wr[f]] + b_hh[wr[f]];
    }

    // ---- owned cells: 2 adjacent per thread (16 rows x 64 cols per wg)
    const int orow  = tid >> 5;                    // 0..15
    const int ocol  = wgin * WCOL + 2 * (tid & 31);
    const int gbrow = g * BSLICE + orow;
    const size_t my_q = (size_t)orow * 256 + (ocol >> 1);   // u64 idx in slice

    float c0 = cx[gbrow * H_SZ + ocol];
    float c1 = cx[gbrow * H_SZ + ocol + 1];
    float h0 = hx[gbrow * H_SZ + ocol];
    float h1 = hx[gbrow * H_SZ + ocol + 1];

    // ---- staging map: thread owns one 64B chunk (row, 8 u64 = 16 fp16 cols)
    const int srow  = tid & 15;
    const int schk  = tid >> 4;                    // 0..31

    // ---- publish h(0) with tag 1 into buffer 0 (fire-and-forget)
    {
        u64t* hb0 = hbuf + (size_t)g * (BSLICE * 256);
        union { _Float16 hp[2]; unsigned u; } pk;
        pk.hp[0] = (_Float16)h0; pk.hp[1] = (_Float16)h1;
        __hip_atomic_store(hb0 + my_q, ((u64t)1u << 32) | pk.u,
                           __ATOMIC_RELAXED, __HIP_MEMORY_SCOPE_AGENT);
    }

    #pragma unroll 1
    for (int t = 0; t < T_STEPS; ++t) {
        // -- x_t @ W_ih^T + bias (h-independent)
        f32x4 acc[2];
        #pragma unroll
        for (int r = 0; r < 4; ++r) {
            const int grow = g * BSLICE + fr_kg * 4 + r;
            const f32x2* xp = (const f32x2*)(x + ((size_t)t * B_SZ + grow) * I_SZ);
            const f32x2 a0 = xp[0], a1 = xp[1], a2 = xp[2], a3 = xp[3], a4 = xp[4];
            #pragma unroll
            for (int f = 0; f < 2; ++f) {
                float s = bias[f];
                s += a0.x*wih[f][0] + a0.y*wih[f][1] + a1.x*wih[f][2] + a1.y*wih[f][3]
                   + a2.x*wih[f][4] + a2.y*wih[f][5] + a3.x*wih[f][6] + a3.y*wih[f][7]
                   + a4.x*wih[f][8] + a4.y*wih[f][9];
                acc[f][r] = s;
            }
        }

        // -- tagged staging: load own 64B chunk, validate 8 tags, retry until
        //    fresh; done lanes drop out (exec mask). Poll IS the data read.
        {
            const u64t* hb = hbuf + ((size_t)(t & 1) * NGRP + g) * (BSLICE * 256);
            const char* sp = (const char*)(hb + (size_t)srow * 256 + schk * 8);
            const unsigned tgt = (unsigned)(t + 1);
            bool done = false;
            for (;;) {
                if (!done) {
                    u32x4 qa, qb, qc, qd;
                    asm volatile(
                        "global_load_dwordx4 %0, %4, off sc0 sc1\n\t"
                        "global_load_dwordx4 %1, %4, off offset:16 sc0 sc1\n\t"
                        "global_load_dwordx4 %2, %4, off offset:32 sc0 sc1\n\t"
                        "global_load_dwordx4 %3, %4, off offset:48 sc0 sc1\n\t"
                        "s_waitcnt vmcnt(0)"
                        : "=&v"(qa), "=&v"(qb), "=&v"(qc), "=&v"(qd)
                        : "v"(sp) : "memory");
                    if (qa.y >= tgt && qa.w >= tgt && qb.y >= tgt && qb.w >= tgt &&
                        qc.y >= tgt && qc.w >= tgt && qd.y >= tgt && qd.w >= tgt) {
                        const u32x4 p0 = {qa.x, qa.z, qb.x, qb.z};
                        const u32x4 p1 = {qc.x, qc.z, qd.x, qd.z};
                        *(u32x4*)&h_stage[srow][schk * 16]     = p0;
                        *(u32x4*)&h_stage[srow][schk * 16 + 8] = p1;
                        done = true;
                    }
                }
                if (__all(done)) break;
                __builtin_amdgcn_s_sleep(1);
            }
        }
        __syncthreads();   // B1: staging visible

        // -- 16 K-chunks: ds_read A-frag, 2 MFMAs each
        #pragma unroll
        for (int c = 0; c < 16; ++c) {
            const f16x8 a = *(const f16x8*)&h_stage[fr_col][c * 32 + fr_kg * 8];
            acc[0] = __builtin_amdgcn_mfma_f32_16x16x32_f16(a, wf[0][c], acc[0], 0, 0, 0);
            acc[1] = __builtin_amdgcn_mfma_f32_16x16x32_f16(a, wf[1][c], acc[1], 0, 0, 0);
        }

        // -- gate pre-activations -> LDS
        #pragma unroll
        for (int f = 0; f < 2; ++f)
            #pragma unroll
            for (int r = 0; r < 4; ++r)
                lds_g[gcL[f]][fr_kg * 4 + r] = acc[f][r];
        __syncthreads();   // B2: gates visible (also fences h_stage WAR)

        // -- c/h update for 2 owned cells; publish tagged h(t+1)
        {
            const int cl = 2 * (tid & 31);
            const float i0 = lds_g[0 * WCOL + cl][orow],     f0 = lds_g[1 * WCOL + cl][orow];
            const float g0 = lds_g[2 * WCOL + cl][orow],     o0 = lds_g[3 * WCOL + cl][orow];
            const float i1 = lds_g[0 * WCOL + cl + 1][orow], f1 = lds_g[1 * WCOL + cl + 1][orow];
            const float g1 = lds_g[2 * WCOL + cl + 1][orow], o1 = lds_g[3 * WCOL + cl + 1][orow];

            const float ig0 = 1.f / (1.f + __expf(-i0));
            const float fg0 = 1.f / (1.f + __expf(-f0));
            const float eg0 = __expf(-2.f * g0);
            const float tg0 = (1.f - eg0) / (1.f + eg0);
            const float og0 = 1.f / (1.f + __expf(-o0));
            const float ig1 = 1.f / (1.f + __expf(-i1));
            const float fg1 = 1.f / (1.f + __expf(-f1));
            const float eg1 = __expf(-2.f * g1);
            const float tg1 = (1.f - eg1) / (1.f + eg1);
            const float og1 = 1.f / (1.f + __expf(-o1));

            c0 = fg0 * c0 + ig0 * tg0;
            c1 = fg1 * c1 + ig1 * tg1;
            const float e0 = __expf(-2.f * c0), e1 = __expf(-2.f * c1);
            h0 = og0 * (1.f - e0) / (1.f + e0);
            h1 = og1 * (1.f - e1) / (1.f + e1);

            if (t < T_STEPS - 1) {
                u64t* hbn = hbuf + ((size_t)((t + 1) & 1) * NGRP + g) * (BSLICE * 256);
                union { _Float16 hp[2]; unsigned u; } pk;
                pk.hp[0] = (_Float16)h0; pk.hp[1] = (_Float16)h1;
                __hip_atomic_store(hbn + my_q,
                                   ((u64t)(unsigned)(t + 2) << 32) | pk.u,
                                   __ATOMIC_RELAXED, __HIP_MEMORY_SCOPE_AGENT);
            }
        }
    }

    // ---- outputs: (h, h, c), each [B,H] f32
    out[gbrow * H_SZ + ocol]                       = h0;
    out[gbrow * H_SZ + ocol + 1]                   = h1;
    out[B_SZ * H_SZ + gbrow * H_SZ + ocol]         = h0;
    out[B_SZ * H_SZ + gbrow * H_SZ + ocol + 1]     = h1;
    out[2 * B_SZ * H_SZ + gbrow * H_SZ + ocol]     = c0;
    out[2 * B_SZ * H_SZ + gbrow * H_SZ + ocol + 1] = c1;
}

extern "C" void kernel_launch(void* const* d_in, const int* in_sizes, int n_in,
                              void* d_out, int out_size, void* d_ws, size_t ws_size,
                              hipStream_t stream) {
    const float* x    = (const float*)d_in[0];
    const float* hx   = (const float*)d_in[1];
    const float* cx   = (const float*)d_in[2];
    const float* W_ih = (const float*)d_in[3];
    const float* W_hh = (const float*)d_in[4];
    const float* b_ih = (const float*)d_in[5];
    const float* b_hh = (const float*)d_in[6];
    float* out = (float*)d_out;

    // ws: [0, 512KB) tagged h double-buffer
    u64t* hbuf = (u64t*)d_ws;

    clear_hbuf_kernel<<<64, 256, 0, stream>>>(hbuf);
    lstm_persistent<<<NWG, NTHR, 0, stream>>>(x, hx, cx, W_ih, W_hh, b_ih, b_hh,
                                              out, hbuf);
}

// Round 10
// 8272.858 us; speedup vs baseline: 1.0073x; 1.0073x over previous
//
#include <hip/hip_runtime.h>
#include <hip/hip_fp16.h>

#define T_STEPS 2048
#define B_SZ 128
#define I_SZ 10
#define H_SZ 512

#define NGRP 8            // batch groups (16 rows each)
#define GWG 8             // wgs per group
#define NWG (NGRP * GWG)  // 64 workgroups
#define BSLICE 16         // batch rows per group
#define WCOL 64           // hidden cols per wg
#define NTHR 512

typedef _Float16 f16x8 __attribute__((ext_vector_type(8)));
typedef float f32x4 __attribute__((ext_vector_type(4)));
typedef float f32x2 __attribute__((ext_vector_type(2)));
typedef unsigned u32x4 __attribute__((ext_vector_type(4)));
typedef unsigned u32x2 __attribute__((ext_vector_type(2)));
typedef unsigned long long u64t;

// Tagged h buffers: [2][NGRP][BSLICE][H/2] u64, u64 = (tag << 32) | 2xfp16.
// MUST be zeroed before every persistent launch: stale tags from a previous
// replay (or 0xAA poison = tag 0xAAAAAAAA) would satisfy the tag check.
__global__ void clear_hbuf_kernel(u64t* p) {
    const int i = blockIdx.x * 256 + threadIdx.x;   // 16384 threads
    #pragma unroll
    for (int k = 0; k < 4; ++k)
        __hip_atomic_store(p + i + k * 16384, 0ull,
                           __ATOMIC_RELAXED, __HIP_MEMORY_SCOPE_AGENT);
}

// Persistent LSTM, tagged-payload sync, COALESCED staging + own-tile shortcut.
//
//   8 independent batch-groups x 8 wgs; wg owns 64 hidden cols (all 4 gates,
//   full K) of its group's 16 batch rows. Tagged u64 = (step tag | 2xfp16),
//   fire-and-forget agent-scope store: the data store IS the flag.
//
//   Staging (the R10 fix): wave w stages bytes [w*4KB,(w+1)*4KB) of the 32KB
//   tagged slice; instruction j reads lanes 0..63 at base+j*1024+lane*16 —
//   64 lanes x 16B = 1KB CONTIGUOUS per instruction (R9 had stride-64B lanes
//   touching 64 lines per instruction). Each lane validates 8 tags across its
//   4 pieces, retries only if stale (done lanes exec-masked off). Own-wg
//   pieces are always-valid (publish wrote them to LDS directly) and are
//   never overwritten from global.
//
// Double-buffer safety (skew <= 1 step): publish at end of step s writes tag
// s+2 into buf[(s+1)&1]. buf[p] transitions tag t+1 -> t+3 only when some wg
// finishes step t+1, which requires staging(t+1): ALL tags t+2 present, i.e.
// every wg finished step t including its staging-reads of buf[p]. So during
// staging(t), buf[p] tags are <t+1 (stale) or exactly t+1 — never ahead.
// Intra-8B atomicity: one store per u64 granule; no torn tag/payload.
//
// h_stage WAR safety: all h_stage reads of step t (MFMA A-frags) precede each
// thread's lds_g writes, which precede B2. Publish-to-LDS and staging writes
// for t+1 happen after B2. One-step skew impossible within a wg (its own
// threads execute the same loop).
__global__ __launch_bounds__(NTHR, 2) void lstm_persistent(
    const float* __restrict__ x,     // [T,B,I]
    const float* __restrict__ hx,    // [B,H]
    const float* __restrict__ cx,    // [B,H]
    const float* __restrict__ W_ih,  // [4H,I]
    const float* __restrict__ W_hh,  // [4H,H]
    const float* __restrict__ b_ih,  // [4H]
    const float* __restrict__ b_hh,  // [4H]
    float* __restrict__ out,         // [3*B*H] = h, h, c
    u64t* hbuf)                      // [2][NGRP][BSLICE][H/2] tagged
{
    __shared__ _Float16 h_stage[BSLICE][520];   // row stride 1040B (8B-aligned)
    __shared__ float lds_g[4 * WCOL][17];       // [gate*64+col][row], padded

    const int wg   = blockIdx.x;
    const int g    = wg >> 3;          // batch group 0..7
    const int wgin = wg & 7;           // wg within group 0..7
    const int tid  = threadIdx.x;
    const int wid  = tid >> 6;         // wave 0..7
    const int lane = tid & 63;
    const int fr_col = lane & 15;
    const int fr_kg  = lane >> 4;      // 0..3

    // ---- this wave's two gate-column fragments (wg covers 256 gate-cols)
    int gcL[2], wr[2];
    #pragma unroll
    for (int f = 0; f < 2; ++f) {
        gcL[f] = wid * 32 + f * 16 + fr_col;              // 0..255
        wr[f]  = (gcL[f] >> 6) * H_SZ + wgin * WCOL + (gcL[f] & 63);
    }

    // ---- W_hh B-fragments: 2 frags x 16 K-chunks, fp16 register-resident
    f16x8 wf[2][16];
    #pragma unroll
    for (int f = 0; f < 2; ++f)
        #pragma unroll
        for (int c = 0; c < 16; ++c) {
            const float* p = W_hh + (size_t)wr[f] * H_SZ + c * 32 + fr_kg * 8;
            f16x8 w;
            #pragma unroll
            for (int e = 0; e < 8; ++e) w[e] = (_Float16)p[e];
            wf[f][c] = w;
        }

    // ---- W_ih rows + combined bias
    float wih[2][I_SZ], bias[2];
    #pragma unroll
    for (int f = 0; f < 2; ++f) {
        #pragma unroll
        for (int i = 0; i < I_SZ; ++i) wih[f][i] = W_ih[wr[f] * I_SZ + i];
        bias[f] = b_ih[wr[f]] + b_hh[wr[f]];
    }

    // ---- owned cells: 2 adjacent per thread (16 rows x 64 cols per wg)
    const int orow  = tid >> 5;                    // 0..15
    const int ocol  = wgin * WCOL + 2 * (tid & 31);
    const int gbrow = g * BSLICE + orow;
    const size_t my_q = (size_t)orow * 256 + (ocol >> 1);   // u64 idx in slice

    float c0 = cx[gbrow * H_SZ + ocol];
    float c1 = cx[gbrow * H_SZ + ocol + 1];
    float h0 = hx[gbrow * H_SZ + ocol];
    float h1 = hx[gbrow * H_SZ + ocol + 1];

    // ---- staging geometry: piece j of this lane = tagged u64 pair
    //      q_idx = wid*512 + j*128 + lane*2 ; row = q>>8 ; pair p = q&255
    int   st_row[4], st_p[4];
    bool  st_own[4];
    #pragma unroll
    for (int j = 0; j < 4; ++j) {
        const int q = wid * 512 + j * 128 + lane * 2;
        st_row[j] = q >> 8;
        st_p[j]   = q & 255;
        st_own[j] = ((st_p[j] >> 5) == wgin);
    }

    // ---- publish h(0): tagged global store + own-region LDS write
    {
        u64t* hb0 = hbuf + (size_t)g * (BSLICE * 256);
        union { _Float16 hp[2]; unsigned u; } pk;
        pk.hp[0] = (_Float16)h0; pk.hp[1] = (_Float16)h1;
        __hip_atomic_store(hb0 + my_q, ((u64t)1u << 32) | pk.u,
                           __ATOMIC_RELAXED, __HIP_MEMORY_SCOPE_AGENT);
        *(unsigned*)&h_stage[orow][ocol] = pk.u;   // LDS shortcut (B1 orders)
    }

    #pragma unroll 1
    for (int t = 0; t < T_STEPS; ++t) {
        // -- x_t @ W_ih^T + bias (h-independent)
        f32x4 acc[2];
        #pragma unroll
        for (int r = 0; r < 4; ++r) {
            const int grow = g * BSLICE + fr_kg * 4 + r;
            const f32x2* xp = (const f32x2*)(x + ((size_t)t * B_SZ + grow) * I_SZ);
            const f32x2 a0 = xp[0], a1 = xp[1], a2 = xp[2], a3 = xp[3], a4 = xp[4];
            #pragma unroll
            for (int f = 0; f < 2; ++f) {
                float s = bias[f];
                s += a0.x*wih[f][0] + a0.y*wih[f][1] + a1.x*wih[f][2] + a1.y*wih[f][3]
                   + a2.x*wih[f][4] + a2.y*wih[f][5] + a3.x*wih[f][6] + a3.y*wih[f][7]
                   + a4.x*wih[f][8] + a4.y*wih[f][9];
                acc[f][r] = s;
            }
        }

        // -- tagged COALESCED staging: 4 x (64 lanes x 16B = 1KB contiguous)
        {
            const u64t* hb = hbuf + ((size_t)(t & 1) * NGRP + g) * (BSLICE * 256);
            const char* sp = (const char*)hb + wid * 4096 + lane * 16;
            const unsigned tgt = (unsigned)(t + 1);
            u32x4 q0, q1, q2, q3;
            bool done = false;
            for (;;) {
                if (!done) {
                    asm volatile(
                        "global_load_dwordx4 %0, %4, off sc0 sc1\n\t"
                        "global_load_dwordx4 %1, %4, off offset:1024 sc0 sc1\n\t"
                        "global_load_dwordx4 %2, %4, off offset:2048 sc0 sc1\n\t"
                        "global_load_dwordx4 %3, %4, off offset:3072 sc0 sc1\n\t"
                        "s_waitcnt vmcnt(0)"
                        : "=&v"(q0), "=&v"(q1), "=&v"(q2), "=&v"(q3)
                        : "v"(sp) : "memory");
                    done = (st_own[0] || (q0.y >= tgt && q0.w >= tgt)) &&
                           (st_own[1] || (q1.y >= tgt && q1.w >= tgt)) &&
                           (st_own[2] || (q2.y >= tgt && q2.w >= tgt)) &&
                           (st_own[3] || (q3.y >= tgt && q3.w >= tgt));
                }
                if (__all(done)) break;
                __builtin_amdgcn_s_sleep(1);
            }
            // de-tag & write payloads to LDS (skip own pieces: already there)
            if (!st_own[0]) *(u32x2*)&h_stage[st_row[0]][st_p[0] * 2] = (u32x2){q0.x, q0.z};
            if (!st_own[1]) *(u32x2*)&h_stage[st_row[1]][st_p[1] * 2] = (u32x2){q1.x, q1.z};
            if (!st_own[2]) *(u32x2*)&h_stage[st_row[2]][st_p[2] * 2] = (u32x2){q2.x, q2.z};
            if (!st_own[3]) *(u32x2*)&h_stage[st_row[3]][st_p[3] * 2] = (u32x2){q3.x, q3.z};
        }
        __syncthreads();   // B1: staging visible

        // -- 16 K-chunks: ds_read A-frag, 2 MFMAs each
        #pragma unroll
        for (int c = 0; c < 16; ++c) {
            const f16x8 a = *(const f16x8*)&h_stage[fr_col][c * 32 + fr_kg * 8];
            acc[0] = __builtin_amdgcn_mfma_f32_16x16x32_f16(a, wf[0][c], acc[0], 0, 0, 0);
            acc[1] = __builtin_amdgcn_mfma_f32_16x16x32_f16(a, wf[1][c], acc[1], 0, 0, 0);
        }

        // -- gate pre-activations -> LDS
        #pragma unroll
        for (int f = 0; f < 2; ++f)
            #pragma unroll
            for (int r = 0; r < 4; ++r)
                lds_g[gcL[f]][fr_kg * 4 + r] = acc[f][r];
        __syncthreads();   // B2: gates visible; also fences ALL h_stage reads

        // -- c/h update for 2 owned cells; publish tagged h(t+1) + LDS shortcut
        {
            const int cl = 2 * (tid & 31);
            const float i0 = lds_g[0 * WCOL + cl][orow],     f0 = lds_g[1 * WCOL + cl][orow];
            const float g0 = lds_g[2 * WCOL + cl][orow],     o0 = lds_g[3 * WCOL + cl][orow];
            const float i1 = lds_g[0 * WCOL + cl + 1][orow], f1 = lds_g[1 * WCOL + cl + 1][orow];
            const float g1 = lds_g[2 * WCOL + cl + 1][orow], o1 = lds_g[3 * WCOL + cl + 1][orow];

            const float ig0 = 1.f / (1.f + __expf(-i0));
            const float fg0 = 1.f / (1.f + __expf(-f0));
            const float eg0 = __expf(-2.f * g0);
            const float tg0 = (1.f - eg0) / (1.f + eg0);
            const float og0 = 1.f / (1.f + __expf(-o0));
            const float ig1 = 1.f / (1.f + __expf(-i1));
            const float fg1 = 1.f / (1.f + __expf(-f1));
            const float eg1 = __expf(-2.f * g1);
            const float tg1 = (1.f - eg1) / (1.f + eg1);
            const float og1 = 1.f / (1.f + __expf(-o1));

            c0 = fg0 * c0 + ig0 * tg0;
            c1 = fg1 * c1 + ig1 * tg1;
            const float e0 = __expf(-2.f * c0), e1 = __expf(-2.f * c1);
            h0 = og0 * (1.f - e0) / (1.f + e0);
            h1 = og1 * (1.f - e1) / (1.f + e1);

            if (t < T_STEPS - 1) {
                u64t* hbn = hbuf + ((size_t)((t + 1) & 1) * NGRP + g) * (BSLICE * 256);
                union { _Float16 hp[2]; unsigned u; } pk;
                pk.hp[0] = (_Float16)h0; pk.hp[1] = (_Float16)h1;
                __hip_atomic_store(hbn + my_q,
                                   ((u64t)(unsigned)(t + 2) << 32) | pk.u,
                                   __ATOMIC_RELAXED, __HIP_MEMORY_SCOPE_AGENT);
                *(unsigned*)&h_stage[orow][ocol] = pk.u;   // own-tile shortcut
            }
        }
    }

    // ---- outputs: (h, h, c), each [B,H] f32
    out[gbrow * H_SZ + ocol]                       = h0;
    out[gbrow * H_SZ + ocol + 1]                   = h1;
    out[B_SZ * H_SZ + gbrow * H_SZ + ocol]         = h0;
    out[B_SZ * H_SZ + gbrow * H_SZ + ocol + 1]     = h1;
    out[2 * B_SZ * H_SZ + gbrow * H_SZ + ocol]     = c0;
    out[2 * B_SZ * H_SZ + gbrow * H_SZ + ocol + 1] = c1;
}

extern "C" void kernel_launch(void* const* d_in, const int* in_sizes, int n_in,
                              void* d_out, int out_size, void* d_ws, size_t ws_size,
                              hipStream_t stream) {
    const float* x    = (const float*)d_in[0];
    const float* hx   = (const float*)d_in[1];
    const float* cx   = (const float*)d_in[2];
    const float* W_ih = (const float*)d_in[3];
    const float* W_hh = (const float*)d_in[4];
    const float* b_ih = (const float*)d_in[5];
    const float* b_hh = (const float*)d_in[6];
    float* out = (float*)d_out;

    // ws: [0, 512KB) tagged h double-buffer
    u64t* hbuf = (u64t*)d_ws;

    clear_hbuf_kernel<<<64, 256, 0, stream>>>(hbuf);
    lstm_persistent<<<NWG, NTHR, 0, stream>>>(x, hx, cx, W_ih, W_hh, b_ih, b_hh,
                                              out, hbuf);
}